// Round 1
// baseline (840.251 us; speedup 1.0000x reference)
//
#include <hip/hip_runtime.h>

#define S_LEN 2048
#define NL 51
#define LS 53
#define ST 51
#define EN 52
#define NBATCH 256
#define L2E 1.4426950408889634f
#define LN2 0.6931471805599453f

// readlane: broadcast lane l's value of v to all lanes (SGPR result)
__device__ __forceinline__ float rlane(float v, int l) {
    return __builtin_bit_cast(float, __builtin_amdgcn_readlane(__builtin_bit_cast(int, v), l));
}

// s[j] = sum_k e[k] * Erow[k], where e[k] lives in lane k, Erow is this lane's row of E.
__device__ __forceinline__ float matvec_row(const float* Erow, float e) {
    float s0 = 0.f, s1 = 0.f, s2 = 0.f, s3 = 0.f;
#pragma unroll
    for (int k = 0; k < 52; k += 4) {
        s0 = fmaf(rlane(e, k + 0), Erow[k + 0], s0);
        s1 = fmaf(rlane(e, k + 1), Erow[k + 1], s1);
        s2 = fmaf(rlane(e, k + 2), Erow[k + 2], s2);
        s3 = fmaf(rlane(e, k + 3), Erow[k + 3], s3);
    }
    s0 = fmaf(rlane(e, 52), Erow[52], s0);
    return (s0 + s1) + (s2 + s3);
}

// One block per batch element. Wave 0 (lanes 0..63, lane j = state j) runs the
// forward recursion in the multiplicative domain:
//   e'[j] = exp(logit[t,j]+Tmax[j]) * s[j] / ssum,  s = E*e,  ssum = s[START]
// (row START of E is all ones because T[START,:] = 100 = Tmax[START]).
// alpha[START] tracks logsumexp(alpha); normalized e[START] == 1 every step,
// so ssum >= 1 and everything stays in fp32 range with no per-step max-reduce.
// Wave 1 computes the gold score (unary gather + transition chain) in parallel.
__global__ __launch_bounds__(128, 1) void crf_kernel(
    const float* __restrict__ logits,   // [256, 2048, 51]
    const int*   __restrict__ labels,   // [256, 2048]
    const int*   __restrict__ lens,     // [256]
    const float* __restrict__ Tr,       // [53, 53]  (to, from)
    float*       __restrict__ out)      // [256]
{
    const int b   = blockIdx.x;
    const int tid = threadIdx.x;
    const int len = lens[b];
    __shared__ float sh_gold;
    __shared__ float sh_norm;

    if (tid >= 64) {
        // ---- wave 1: gold score ----
        const int lid = tid - 64;
        const int* lb = labels + (long)b * S_LEN;
        const float* lg = logits + (long)b * S_LEN * NL;
        float p = 0.f;
        for (int t = lid; t < len; t += 64) {
            const int lab  = lb[t];
            const int prev = (t == 0) ? ST : lb[t - 1];
            p += lg[(long)t * NL + lab] + Tr[lab * LS + prev];
        }
        if (lid == 0) p += Tr[EN * LS + lb[len - 1]];   // final transition to END
#pragma unroll
        for (int off = 32; off > 0; off >>= 1)
            p += __shfl_down(p, off, 64);
        if (lid == 0) sh_gold = p;
    } else {
        // ---- wave 0: forward scan (norm score) ----
        const int j   = tid;
        const int row = (j < LS) ? j : (LS - 1);   // clamp lanes 53..63 (never read)
        float Erow[LS];
        float tmax = -1e30f;
#pragma unroll
        for (int k = 0; k < LS; ++k) {
            Erow[k] = Tr[row * LS + k];
            tmax = fmaxf(tmax, Erow[k]);
        }
#pragma unroll
        for (int k = 0; k < LS; ++k)
            Erow[k] = __builtin_amdgcn_exp2f((Erow[k] - tmax) * L2E);

        const float* lg = logits + (long)b * S_LEN * NL;
        float e    = (j == ST) ? 1.f : 0.f;   // alpha0: 0 at START, -100 elsewhere (exp(-100)~0)
        float off2 = 0.f;                     // sum of log2(ssum) == alpha[START] in log2 units
        float lgt  = (j < NL) ? lg[j] : -100.f;
        float gexp = __builtin_amdgcn_exp2f((lgt + tmax) * L2E);

#pragma unroll 1
        for (int t = 0; t < len; ++t) {
            // prefetch next step's logit (off the critical chain)
            float nlg = -100.f;
            if (j < NL && t + 1 < len) nlg = lg[(long)(t + 1) * NL + j];

            float s    = matvec_row(Erow, e);
            float ssum = rlane(s, ST);                       // = sum_k e[k], >= 1
            off2 += __builtin_amdgcn_logf(ssum);             // independent chain
            e = gexp * s * __builtin_amdgcn_rcpf(ssum);
            gexp = __builtin_amdgcn_exp2f((nlg + tmax) * L2E);
        }

        // norm = logsumexp_j(alpha[j] + T[END, j]) -- one more matvec, take row END
        float s     = matvec_row(Erow, e);
        float sEnd  = rlane(s, EN);
        float tmEnd = rlane(tmax, EN);
        float norm  = (off2 + __builtin_amdgcn_logf(sEnd)) * LN2 + tmEnd;
        if (j == 0) sh_norm = norm;
    }
    __syncthreads();
    if (tid == 0) out[b] = sh_gold - sh_norm;
}

extern "C" void kernel_launch(void* const* d_in, const int* in_sizes, int n_in,
                              void* d_out, int out_size, void* d_ws, size_t ws_size,
                              hipStream_t stream) {
    const float* logits = (const float*)d_in[0];
    const int*   labels = (const int*)d_in[1];
    const int*   lens   = (const int*)d_in[2];
    const float* Tr     = (const float*)d_in[3];
    float*       out    = (float*)d_out;
    crf_kernel<<<NBATCH, 128, 0, stream>>>(logits, labels, lens, Tr, out);
}

// Round 2
// 549.183 us; speedup vs baseline: 1.5300x; 1.5300x over previous
//
#include <hip/hip_runtime.h>

#define S_LEN 2048
#define NL 51
#define LS 53
#define ST 51
#define EN 52
#define NBATCH 256
#define L2E 1.4426950408889634f
#define LN2 0.6931471805599453f

// readlane: broadcast lane l's value of v to all lanes (SGPR result)
__device__ __forceinline__ float rlane(float v, int l) {
    return __builtin_bit_cast(float, __builtin_amdgcn_readlane(__builtin_bit_cast(int, v), l));
}

// s[j] = sum_k e[k] * Erow[k]; e[k] lives in lane k, Erow is this lane's row of E.
__device__ __forceinline__ float matvec_row(const float* Erow, float e) {
    float s0 = 0.f, s1 = 0.f, s2 = 0.f, s3 = 0.f;
#pragma unroll
    for (int k = 0; k < 52; k += 4) {
        s0 = fmaf(rlane(e, k + 0), Erow[k + 0], s0);
        s1 = fmaf(rlane(e, k + 1), Erow[k + 1], s1);
        s2 = fmaf(rlane(e, k + 2), Erow[k + 2], s2);
        s3 = fmaf(rlane(e, k + 3), Erow[k + 3], s3);
    }
    s0 = fmaf(rlane(e, 52), Erow[52], s0);
    return (s0 + s1) + (s2 + s3);
}

// One block per batch element. Wave 0 runs the forward recursion in the
// multiplicative domain with a LAGGED divisor:
//   e_{t+1} = s_t * q_t,   s_t = E e_t,   q_t = gexp_t * rcp(ssum_{t-1})
// where ssum_t = s_t[START] (row START of E is all-ones). Every divisor that
// is actually applied has its log2 accumulated into off2 -> exact rescaling.
// Logits are register-prefetched 8..15 steps ahead (buf/nbuf double buffer)
// so the ~200-900 cyc global-load latency is fully hidden.
// Wave 1 computes the gold score in parallel.
__global__ __launch_bounds__(128, 1) void crf_kernel(
    const float* __restrict__ logits,   // [256, 2048, 51]
    const int*   __restrict__ labels,   // [256, 2048]
    const int*   __restrict__ lens,     // [256]
    const float* __restrict__ Tr,       // [53, 53]  (to, from)
    float*       __restrict__ out)      // [256]
{
    const int b   = blockIdx.x;
    const int tid = threadIdx.x;
    const int len = lens[b];
    __shared__ float sh_gold;
    __shared__ float sh_norm;

    if (tid >= 64) {
        // ---- wave 1: gold score ----
        const int lid = tid - 64;
        const int* lb = labels + (long)b * S_LEN;
        const float* lg = logits + (long)b * S_LEN * NL;
        float p = 0.f;
        for (int t = lid; t < len; t += 64) {
            const int lab  = lb[t];
            const int prev = (t == 0) ? ST : lb[t - 1];
            p += lg[(long)t * NL + lab] + Tr[lab * LS + prev];
        }
        if (lid == 0) p += Tr[EN * LS + lb[len - 1]];   // final transition to END
#pragma unroll
        for (int off = 32; off > 0; off >>= 1)
            p += __shfl_down(p, off, 64);
        if (lid == 0) sh_gold = p;
    } else {
        // ---- wave 0: forward scan (norm score) ----
        const int j   = tid;
        const int row = (j < LS) ? j : (LS - 1);   // clamp lanes 53..63 (never read)
        float Erow[LS];
        float tmax = -1e30f;
#pragma unroll
        for (int k = 0; k < LS; ++k) {
            Erow[k] = Tr[row * LS + k];
            tmax = fmaxf(tmax, Erow[k]);
        }
#pragma unroll
        for (int k = 0; k < LS; ++k)
            Erow[k] = __builtin_amdgcn_exp2f((Erow[k] - tmax) * L2E);

        const float* lg = logits + (long)b * S_LEN * NL;
        const bool act = (j < NL);

        float buf[8], nbuf[8];
#pragma unroll
        for (int i = 0; i < 8; ++i)
            buf[i] = act ? lg[i * NL + j] : -100.f;   // steps 0..7 (always in-bounds)

        float e     = (j == ST) ? 1.f : 0.f;  // exp(alpha0)
        float off2  = 0.f;                    // sum of log2 of APPLIED divisors
        float lprev = 0.f;                    // log2 of divisor inside current q
        float q     = __builtin_amdgcn_exp2f((buf[0] + tmax) * L2E);  // gexp_0 * 1

        int t = 0;
        while (t + 8 <= len) {
            // prefetch steps t+8 .. t+15 (issued ~1800 cyc before use)
#pragma unroll
            for (int i = 0; i < 8; ++i) {
                int ti = t + 8 + i;
                ti = (ti < S_LEN) ? ti : (S_LEN - 1);   // clamp: stays in-bounds, unused if >= len
                nbuf[i] = act ? lg[(long)ti * NL + j] : -100.f;
            }
#pragma unroll
            for (int i = 0; i < 8; ++i) {
                float s = matvec_row(Erow, e);
                e = s * q;                               // apply gexp_t * rinv_{t-1}
                float ssum = rlane(s, ST);
                off2 += lprev;                           // log the divisor just applied
                lprev = __builtin_amdgcn_logf(ssum);     // v_log_f32 = log2
                float nl = (i < 7) ? buf[i + 1] : nbuf[0];
                q = __builtin_amdgcn_exp2f((nl + tmax) * L2E) * __builtin_amdgcn_rcpf(ssum);
            }
#pragma unroll
            for (int i = 0; i < 8; ++i) buf[i] = nbuf[i];
            t += 8;
        }
        // tail: < 8 steps, buf[i] = logit[t+i]
#pragma unroll
        for (int i = 0; i < 8; ++i) {
            if (t + i < len) {
                float s = matvec_row(Erow, e);
                e = s * q;
                float ssum = rlane(s, ST);
                off2 += lprev;
                lprev = __builtin_amdgcn_logf(ssum);
                float nl = buf[(i + 1) & 7];
                q = __builtin_amdgcn_exp2f((nl + tmax) * L2E) * __builtin_amdgcn_rcpf(ssum);
            }
        }

        // norm = logsumexp_j(alpha[j] + T[END, j]) -- one more matvec, row END
        float s     = matvec_row(Erow, e);
        float sEnd  = rlane(s, EN);
        float tmEnd = rlane(tmax, EN);
        float norm  = (off2 + __builtin_amdgcn_logf(sEnd)) * LN2 + tmEnd;
        if (j == 0) sh_norm = norm;
    }
    __syncthreads();
    if (tid == 0) out[b] = sh_gold - sh_norm;
}

extern "C" void kernel_launch(void* const* d_in, const int* in_sizes, int n_in,
                              void* d_out, int out_size, void* d_ws, size_t ws_size,
                              hipStream_t stream) {
    const float* logits = (const float*)d_in[0];
    const int*   labels = (const int*)d_in[1];
    const int*   lens   = (const int*)d_in[2];
    const float* Tr     = (const float*)d_in[3];
    float*       out    = (float*)d_out;
    crf_kernel<<<NBATCH, 128, 0, stream>>>(logits, labels, lens, Tr, out);
}

// Round 3
// 541.785 us; speedup vs baseline: 1.5509x; 1.0137x over previous
//
#include <hip/hip_runtime.h>

#define S_LEN 2048
#define NL 51
#define LS 53
#define ST 51
#define EN 52
#define NBATCH 256
#define L2E 1.4426950408889634f
#define LN2 0.6931471805599453f

typedef float f32x4 __attribute__((ext_vector_type(4)));

// readlane: broadcast lane l's value of v to all lanes (SGPR result)
__device__ __forceinline__ float rlane(float v, int l) {
    return __builtin_bit_cast(float, __builtin_amdgcn_readlane(__builtin_bit_cast(int, v), l));
}

// One block per batch element. Wave 0 runs the forward recursion in the
// multiplicative domain with a LAGGED divisor (same math as R2, which passed):
//   e_{t+1} = s_t * q_t,   s_t = E e_t,   q_t = gexp_t * rcp(ssum_{t-1})
// ssum = s[START] (row START of E is all-ones). Applied divisors' log2 go to off2.
//
// R3 change: E-row lives in 14 named f32x4 VGPRs (R1/R2 left Erow[] in scratch —
// VGPR_Count=36 proved it), and the e-broadcast goes through LDS
// (1 ds_write_b32 + 14 ds_read_b128 broadcasts) instead of 53 readlanes.
// Same-wave DS ops are pipe-ordered, so no barrier is needed.
// Lanes/states 53..55 are zero-padded: their e stays 0 (q==0 via tmax=-1e30),
// so the 56-wide vector sum equals the 53-state sum exactly.
__global__ __launch_bounds__(128, 1) void crf_kernel(
    const float* __restrict__ logits,   // [256, 2048, 51]
    const int*   __restrict__ labels,   // [256, 2048]
    const int*   __restrict__ lens,     // [256]
    const float* __restrict__ Tr,       // [53, 53]  (to, from)
    float*       __restrict__ out)      // [256]
{
    const int b   = blockIdx.x;
    const int tid = threadIdx.x;
    const int len = lens[b];
    __shared__ float sh_gold;
    __shared__ float sh_norm;
    __shared__ __align__(16) float sh_e[56];

    if (tid >= 64) {
        // ---- wave 1: gold score ----
        const int lid = tid - 64;
        const int* lb = labels + (long)b * S_LEN;
        const float* lg = logits + (long)b * S_LEN * NL;
        float p = 0.f;
        for (int t = lid; t < len; t += 64) {
            const int lab  = lb[t];
            const int prev = (t == 0) ? ST : lb[t - 1];
            p += lg[(long)t * NL + lab] + Tr[lab * LS + prev];
        }
        if (lid == 0) p += Tr[EN * LS + lb[len - 1]];   // final transition to END
#pragma unroll
        for (int off = 32; off > 0; off >>= 1)
            p += __shfl_down(p, off, 64);
        if (lid == 0) sh_gold = p;
    } else {
        // ---- wave 0: forward scan (norm score) ----
        const int j = tid;
        const float* trow = Tr + j * LS;

        // E-row of this lane in 14 named f32x4 registers (guaranteed VGPRs).
        f32x4 er0, er1, er2, er3, er4, er5, er6, er7, er8, er9, er10, er11, er12, er13;
#define GT(K)    (((j < LS) && ((K) < LS)) ? trow[(K)] : -1e30f)
#define LD4(V,B) { V.x = GT(B); V.y = GT((B)+1); V.z = GT((B)+2); V.w = GT((B)+3); }
        LD4(er0, 0)  LD4(er1, 4)  LD4(er2, 8)   LD4(er3, 12)
        LD4(er4, 16) LD4(er5, 20) LD4(er6, 24)  LD4(er7, 28)
        LD4(er8, 32) LD4(er9, 36) LD4(er10, 40) LD4(er11, 44)
        LD4(er12, 48) LD4(er13, 52)
#undef GT
#undef LD4
        float tmax = -1e30f;
#define MX4(V) tmax = fmaxf(tmax, fmaxf(fmaxf(V.x, V.y), fmaxf(V.z, V.w)));
        MX4(er0) MX4(er1) MX4(er2) MX4(er3) MX4(er4) MX4(er5) MX4(er6)
        MX4(er7) MX4(er8) MX4(er9) MX4(er10) MX4(er11) MX4(er12) MX4(er13)
#undef MX4
        // er = exp(T - tmax).  (j>=53: tmax=-1e30 -> er=1, harmless since
        // those lanes' q==0 keeps e==0 and sh_e[53..55]==0 kills their columns.)
#define EX4(V) { V.x = __builtin_amdgcn_exp2f((V.x - tmax) * L2E); \
                 V.y = __builtin_amdgcn_exp2f((V.y - tmax) * L2E); \
                 V.z = __builtin_amdgcn_exp2f((V.z - tmax) * L2E); \
                 V.w = __builtin_amdgcn_exp2f((V.w - tmax) * L2E); }
        EX4(er0) EX4(er1) EX4(er2) EX4(er3) EX4(er4) EX4(er5) EX4(er6)
        EX4(er7) EX4(er8) EX4(er9) EX4(er10) EX4(er11) EX4(er12) EX4(er13)
#undef EX4

        const float* lg = logits + (long)b * S_LEN * NL;
        const bool act = (j < NL);

        float buf[8], nbuf[8];
#pragma unroll
        for (int i = 0; i < 8; ++i)
            buf[i] = act ? lg[i * NL + j] : -100.f;   // steps 0..7 (always in-bounds)

        float e     = (j == ST) ? 1.f : 0.f;  // exp(alpha0); lanes 53..63 -> 0
        float off2  = 0.f;                    // sum of log2 of APPLIED divisors
        float lprev = 0.f;                    // log2 of divisor inside current q
        float q     = __builtin_amdgcn_exp2f((buf[0] + tmax) * L2E);  // gexp_0 * 1

        // broadcast e via LDS, 14x ds_read_b128, pk-fma accumulate
#define MATVEC(SOUT) { \
            if (j < 56) sh_e[j] = e; \
            const f32x4* sp = (const f32x4*)sh_e; \
            f32x4 a0 = sp[0] * er0, a1 = sp[1] * er1, a2 = sp[2] * er2, a3 = sp[3] * er3; \
            a0 += sp[4]  * er4;  a1 += sp[5]  * er5;  a2 += sp[6]  * er6;  a3 += sp[7]  * er7; \
            a0 += sp[8]  * er8;  a1 += sp[9]  * er9;  a2 += sp[10] * er10; a3 += sp[11] * er11; \
            a0 += sp[12] * er12; a1 += sp[13] * er13; \
            f32x4 aa = (a0 + a1) + (a2 + a3); \
            SOUT = (aa.x + aa.y) + (aa.z + aa.w); }

#define STEP(NLOGIT) { \
            float s; MATVEC(s); \
            e = s * q; \
            float ssum = rlane(s, ST); \
            off2 += lprev; \
            lprev = __builtin_amdgcn_logf(ssum); \
            q = __builtin_amdgcn_exp2f(((NLOGIT) + tmax) * L2E) * __builtin_amdgcn_rcpf(ssum); }

        int t = 0;
        while (t + 8 <= len) {
            // prefetch steps t+8 .. t+15 (~8 steps ahead of use)
#pragma unroll
            for (int i = 0; i < 8; ++i) {
                int ti = t + 8 + i;
                ti = (ti < S_LEN) ? ti : (S_LEN - 1);   // clamp: in-bounds, unused if >= len
                nbuf[i] = act ? lg[(long)ti * NL + j] : -100.f;
            }
#pragma unroll
            for (int i = 0; i < 8; ++i) {
                float nl = (i < 7) ? buf[i + 1] : nbuf[0];
                STEP(nl)
            }
#pragma unroll
            for (int i = 0; i < 8; ++i) buf[i] = nbuf[i];
            t += 8;
        }
        // tail: < 8 steps
#pragma unroll
        for (int i = 0; i < 8; ++i) {
            if (t + i < len) {
                float nl = buf[(i + 1) & 7];
                STEP(nl)
            }
        }

        // norm = logsumexp_j(alpha[j] + T[END, j]) -- one more matvec, row END
        float s; MATVEC(s);
        float sEnd  = rlane(s, EN);
        float tmEnd = rlane(tmax, EN);
        float norm  = (off2 + __builtin_amdgcn_logf(sEnd)) * LN2 + tmEnd;
        if (j == 0) sh_norm = norm;
#undef STEP
#undef MATVEC
    }
    __syncthreads();
    if (tid == 0) out[b] = sh_gold - sh_norm;
}

extern "C" void kernel_launch(void* const* d_in, const int* in_sizes, int n_in,
                              void* d_out, int out_size, void* d_ws, size_t ws_size,
                              hipStream_t stream) {
    const float* logits = (const float*)d_in[0];
    const int*   labels = (const int*)d_in[1];
    const int*   lens   = (const int*)d_in[2];
    const float* Tr     = (const float*)d_in[3];
    float*       out    = (float*)d_out;
    crf_kernel<<<NBATCH, 128, 0, stream>>>(logits, labels, lens, Tr, out);
}